// Round 3
// baseline (356.364 us; speedup 1.0000x reference)
//
#include <hip/hip_runtime.h>

// FastVCompressor: VQ nearest-code + gather + sparsity mask.
//   keys [4,4096,1024] f32, values [4,4096,1024] f32, codebook [256,1024] f32
// out = concat(keys_c, values_c) f32.
//
// R8: occupancy push for argmin (2 -> 3 blocks/CU).
//   - argmin: BN=128 codes/block (LDS 48 KB: B dbuf 32 KB + A dbuf 16 KB),
//     grid (256, 4) = row-tile x {tensor, code-half}. Each wave: 2 ct quads,
//     acc[4][2], 24 MFMA/step. Writes per-row best-2 PARTIALS (bv,bc,b2)
//     per code-half instead of final fidx. setprio(1) around MFMA cluster.
//   - gather: merges the two half partials in-register (exact best-2 merge),
//     gathers + masks, appends margin-flagged rows to worklist. No fidx buf.
//   - recheck: exact fp64 argmin of flagged rows, writes the output row
//     DIRECTLY (cb[bc] * mask) -> no combine kernel needed; still 5 dispatches.

#define H 1024
#define NC 256
#define MT 64
#define THREADS 256
#define BK 32
#define KSTEPS (H / BK)   // 32
#define WLCAP 32768

typedef __attribute__((ext_vector_type(8))) short bf16x8;
typedef __attribute__((ext_vector_type(4))) float f32x4;

static __device__ inline unsigned short f2bf_rne(float f) {
    unsigned u = __float_as_uint(f);
    u += 0x7FFF + ((u >> 16) & 1);
    return (unsigned short)(u >> 16);
}
static __device__ inline float bf2f(unsigned short h) {
    return __uint_as_float((unsigned)h << 16);
}
static __device__ inline void gl_lds16(const void* g, void* l) {
    __builtin_amdgcn_global_load_lds(
        (const __attribute__((address_space(1))) unsigned int*)g,
        (__attribute__((address_space(3))) unsigned int*)l, 16, 0, 0);
}

// ---------------- prep: c_sq + packed-k float4 codebook (for fp64 recheck) --
// wt4 layout: float4 index (k>>2)*NC + code  holds cb[code][4k..4k+3].
__global__ __launch_bounds__(256) void prep_kernel(const float* __restrict__ cb,
                                                   float* __restrict__ c_sq,
                                                   float4* __restrict__ wt4,
                                                   int* __restrict__ wl_count) {
    const int b = blockIdx.x;
    const int t = threadIdx.x;
    if (b == 0 && t == 0) wl_count[0] = 0;
    const float4 v = *(const float4*)(cb + (size_t)b * H + 4 * t);
    wt4[(size_t)t * NC + b] = v;
    float s = v.x * v.x + v.y * v.y + v.z * v.z + v.w * v.w;
    #pragma unroll
    for (int off = 32; off > 0; off >>= 1) s += __shfl_down(s, off);
    __shared__ float red[4];
    if ((t & 63) == 0) red[t >> 6] = s;
    __syncthreads();
    if (t == 0) c_sq[b] = red[0] + red[1] + red[2] + red[3];
}

// ---------------- prep: codebook -> frag-major bf16 hi/lo ----------------
// wbuf uint4 index within slice s: (ct*2 + h)*64 + lane ; slice = 2048 uint4.
// B-frag: lane l of tile ct holds B[k = s*32 + (l>>4)*8 + j][n = ct*16 + (l&15)]
__global__ __launch_bounds__(256) void prep_frag_kernel(const float* __restrict__ cb,
                                                        unsigned short* __restrict__ wbuf) {
    const int s = blockIdx.x;
    const int t = threadIdx.x;
    const int l = t & 63;
    #pragma unroll
    for (int it = 0; it < 4; ++it) {
        const int ct = it * 4 + (t >> 6);
        const int code = ct * 16 + (l & 15);
        const int k0 = s * BK + (l >> 4) * 8;
        const float4 a = *(const float4*)(cb + (size_t)code * H + k0);
        const float4 b = *(const float4*)(cb + (size_t)code * H + k0 + 4);
        float x[8] = {a.x, a.y, a.z, a.w, b.x, b.y, b.z, b.w};
        unsigned short hi[8], lo[8];
        #pragma unroll
        for (int j = 0; j < 8; ++j) {
            hi[j] = f2bf_rne(x[j]);
            lo[j] = f2bf_rne(x[j] - bf2f(hi[j]));
        }
        const size_t base = ((((size_t)s * 16 + ct) * 2) * 64 + l) * 8;
        *(uint4*)(wbuf + base) = *(const uint4*)hi;
        *(uint4*)(wbuf + base + 64 * 8) = *(const uint4*)lo;
    }
}

// ---------------- main: GEMM-argmin over 128 codes, writes best-2 partials --
__global__ __launch_bounds__(THREADS, 3) void argmin_kernel(
    const float* __restrict__ keys, const float* __restrict__ vals,
    const unsigned short* __restrict__ wbuf, const float* __restrict__ c_sq,
    float* __restrict__ pbv, float* __restrict__ pb2, int* __restrict__ pbc) {
    __shared__ uint4 b_u4[2][1024];   // 32 KB: B dbuf (128 codes), frag-major
    __shared__ uint4 a_u4[2][512];    // 16 KB: A dbuf, (rt*2+h)*64 + slot

    const int t = threadIdx.x;
    const int lane = t & 63;
    const int w = t >> 6;            // wave 0..3: local ct pair {w*2, w*2+1}
    const int tensor = blockIdx.y >> 1;
    const int half = blockIdx.y & 1; // global ct = half*8 + w*2 + j
    const float* __restrict__ X = tensor ? vals : keys;
    const int row0 = blockIdx.x * MT;

    // A staging slot: thread t stages (rt = t>>6, slot = lane)
    const int s_row = row0 + (t >> 6) * 16 + (lane & 15);
    const int s_kq = (lane >> 4) * 8;
    const float* __restrict__ xrow = X + (size_t)s_row * H + s_kq;

    f32x4 acc[4][2];
    #pragma unroll
    for (int i = 0; i < 4; ++i)
        #pragma unroll
        for (int j = 0; j < 2; ++j) acc[i][j] = (f32x4){0.f, 0.f, 0.f, 0.f};

    // ---- prologue: stage step 0, prefetch step 1 ----
    {
        const float4 c0 = *(const float4*)(xrow);
        const float4 c1 = *(const float4*)(xrow + 4);
        float x[8] = {c0.x, c0.y, c0.z, c0.w, c1.x, c1.y, c1.z, c1.w};
        unsigned short hi[8], lo[8];
        #pragma unroll
        for (int j = 0; j < 8; ++j) {
            hi[j] = f2bf_rne(x[j]);
            lo[j] = f2bf_rne(x[j] - bf2f(hi[j]));
        }
        a_u4[0][((t >> 6) * 2 + 0) * 64 + lane] = *(const uint4*)hi;
        a_u4[0][((t >> 6) * 2 + 1) * 64 + lane] = *(const uint4*)lo;
        const char* gsrc = (const char*)wbuf + (size_t)(half * 8 + w * 2) * 2048 + lane * 16;
        char* ldst = (char*)&b_u4[0][0] + w * 4096;
        #pragma unroll
        for (int c = 0; c < 4; ++c) gl_lds16(gsrc + c * 1024, ldst + c * 1024);
    }
    float4 nx0 = *(const float4*)(xrow + BK);
    float4 nx1 = *(const float4*)(xrow + BK + 4);
    __syncthreads();

    for (int s = 0; s < KSTEPS; ++s) {
        const int p = s & 1;
        if (s + 1 < KSTEPS) {
            // stage step s+1 into buffer p^1 (stale since end of step s-1)
            float x[8] = {nx0.x, nx0.y, nx0.z, nx0.w, nx1.x, nx1.y, nx1.z, nx1.w};
            unsigned short hi[8], lo[8];
            #pragma unroll
            for (int j = 0; j < 8; ++j) {
                hi[j] = f2bf_rne(x[j]);
                lo[j] = f2bf_rne(x[j] - bf2f(hi[j]));
            }
            a_u4[p ^ 1][((t >> 6) * 2 + 0) * 64 + lane] = *(const uint4*)hi;
            a_u4[p ^ 1][((t >> 6) * 2 + 1) * 64 + lane] = *(const uint4*)lo;
            const char* gsrc = (const char*)wbuf + (size_t)(s + 1) * 32768 +
                               (size_t)(half * 8 + w * 2) * 2048 + lane * 16;
            char* ldst = (char*)&b_u4[p ^ 1][0] + w * 4096;
            #pragma unroll
            for (int c = 0; c < 4; ++c) gl_lds16(gsrc + c * 1024, ldst + c * 1024);
        }
        if (s + 2 < KSTEPS) {
            nx0 = *(const float4*)(xrow + (s + 2) * BK);
            nx1 = *(const float4*)(xrow + (s + 2) * BK + 4);
        }
        // compute on buffer p
        bf16x8 ah[4], al[4], bh[2], bl[2];
        #pragma unroll
        for (int i = 0; i < 4; ++i) {
            ah[i] = ((const bf16x8*)&a_u4[p][0])[(i * 2 + 0) * 64 + lane];
            al[i] = ((const bf16x8*)&a_u4[p][0])[(i * 2 + 1) * 64 + lane];
        }
        #pragma unroll
        for (int j = 0; j < 2; ++j) {
            const int ctl = w * 2 + j;
            bh[j] = ((const bf16x8*)&b_u4[p][0])[(ctl * 2 + 0) * 64 + lane];
            bl[j] = ((const bf16x8*)&b_u4[p][0])[(ctl * 2 + 1) * 64 + lane];
        }
        __builtin_amdgcn_s_setprio(1);
        #pragma unroll
        for (int i = 0; i < 4; ++i)
            #pragma unroll
            for (int j = 0; j < 2; ++j) {
                acc[i][j] = __builtin_amdgcn_mfma_f32_16x16x32_bf16(ah[i], bl[j], acc[i][j], 0, 0, 0);
                acc[i][j] = __builtin_amdgcn_mfma_f32_16x16x32_bf16(al[i], bh[j], acc[i][j], 0, 0, 0);
                acc[i][j] = __builtin_amdgcn_mfma_f32_16x16x32_bf16(ah[i], bh[j], acc[i][j], 0, 0, 0);
            }
        __builtin_amdgcn_s_setprio(0);
        __syncthreads();
    }

    // ---- per-row argmin with best-2 tracking (over this block's 128 codes) --
    float csq[2];
    #pragma unroll
    for (int j = 0; j < 2; ++j) csq[j] = c_sq[half * 128 + w * 32 + j * 16 + (lane & 15)];

    float* rv = (float*)&a_u4[0][0];        // [64][4]
    int* ri = (int*)&a_u4[0][0] + 256;      // [64][4]
    float* r2 = (float*)&a_u4[0][0] + 512;  // [64][4]

    #pragma unroll
    for (int i = 0; i < 4; ++i) {
        #pragma unroll
        for (int r = 0; r < 4; ++r) {
            const int row = i * 16 + (lane >> 4) * 4 + r;
            float bv = csq[0] - 2.0f * acc[i][0][r];
            int bc = half * 128 + w * 32 + (lane & 15);
            float b2 = 3.4e38f;
            {
                const float v = csq[1] - 2.0f * acc[i][1][r];
                if (v < bv) { b2 = bv; bv = v; bc += 16; }
                else b2 = v;
            }
            #pragma unroll
            for (int off = 1; off < 16; off <<= 1) {
                const float ov = __shfl_xor(bv, off);
                const int oc = __shfl_xor(bc, off);
                const float ov2 = __shfl_xor(b2, off);
                const float nb2 = fminf(fmaxf(bv, ov), fminf(b2, ov2));
                if (ov < bv || (ov == bv && oc < bc)) { bv = ov; bc = oc; }
                b2 = nb2;
            }
            if ((lane & 15) == 0) {
                rv[row * 4 + w] = bv;
                ri[row * 4 + w] = bc;
                r2[row * 4 + w] = b2;
            }
        }
    }
    __syncthreads();
    if (t < MT) {
        float bv = rv[t * 4];
        int bc = ri[t * 4];
        float b2 = r2[t * 4];
        #pragma unroll
        for (int g = 1; g < 4; ++g) {        // ascending wave = ascending codes
            const float v = rv[t * 4 + g];
            const int c = ri[t * 4 + g];
            const float v2 = r2[t * 4 + g];
            const float nb2 = fminf(fmaxf(bv, v), fminf(b2, v2));
            if (v < bv || (v == bv && c < bc)) { bv = v; bc = c; }
            b2 = nb2;
        }
        const size_t rowg = (size_t)tensor * (gridDim.x * MT) + row0 + t;
        const size_t pi = rowg * 2 + half;
        pbv[pi] = bv;
        pb2[pi] = b2;
        pbc[pi] = bc;
    }
}

// ---------------- gather: merge half partials + gather + flag ----------------
__global__ __launch_bounds__(256) void gather_kernel(
    const float* __restrict__ cb, const float* __restrict__ c_sq,
    const float* __restrict__ pbv, const float* __restrict__ pb2,
    const int* __restrict__ pbc, int* __restrict__ wl, int* __restrict__ wl_count,
    float* __restrict__ out) {
    const int t = threadIdx.x;
    const int row = blockIdx.x * 4 + (t >> 6);
    const int lane = t & 63;

    const size_t i0 = (size_t)row * 2;
    const float bv0 = pbv[i0], bv1 = pbv[i0 + 1];
    const float b20 = pb2[i0], b21 = pb2[i0 + 1];
    int bc = pbc[i0];
    float bv = bv0;
    if (bv1 < bv0) { bv = bv1; bc = pbc[i0 + 1]; }   // strict: tie keeps half0 (lower code)
    const float b2 = fminf(fmaxf(bv0, bv1), fminf(b20, b21));

    if (lane == 0 && (b2 - bv < 0.15f)) {
        const int pos = atomicAdd(wl_count, 1);
        if (pos < WLCAP) wl[pos] = row;
    }

    const float m = (c_sq[bc] > 0.01f) ? 1.0f : 0.0f;
    const float4* __restrict__ src = (const float4*)(cb + (size_t)bc * H);
    float4* __restrict__ dst = (float4*)(out + (size_t)row * H);
    #pragma unroll
    for (int j = 0; j < 4; ++j) {
        float4 v = src[lane + 64 * j];
        v.x *= m; v.y *= m; v.z *= m; v.w *= m;
        dst[lane + 64 * j] = v;
    }
}

// ---------------- exact fp64 recheck of worklist rows, writes out directly ---
__global__ __launch_bounds__(256) void recheck_kernel(
    const float* __restrict__ keys, const float* __restrict__ vals,
    const float4* __restrict__ wt4, const float* __restrict__ c_sq,
    const float* __restrict__ cb, const int* __restrict__ wl,
    const int* __restrict__ wl_count, float* __restrict__ out) {
    __shared__ float xs[4][H];       // 16 KB
    __shared__ double bvs[16];
    __shared__ int bcs[16];
    __shared__ int bcf[4];

    const int t = threadIdx.x;
    const int w = t >> 6;
    const int lane = t & 63;
    int n = wl_count[0];
    if (n > WLCAP) n = WLCAP;
    if (n == 0) return;

    for (int base = blockIdx.x * 4; base < n; base += gridDim.x * 4) {
        // wave w loads row (base + w); clamp duplicates are computed but not written
        {
            const int idx = base + w;
            const int rowg = wl[idx < n ? idx : n - 1];
            const float* __restrict__ X =
                ((rowg >> 14) ? vals : keys) + (size_t)(rowg & 16383) * H;
            #pragma unroll
            for (int j = 0; j < 4; ++j)
                ((float4*)&xs[w][0])[lane + 64 * j] = ((const float4*)X)[lane + 64 * j];
        }
        __syncthreads();

        double dd0 = 0.0, dd1 = 0.0, dd2 = 0.0, dd3 = 0.0;
        for (int k0 = 0; k0 < H; k0 += 4) {
            const float4 wv = wt4[(size_t)(k0 >> 2) * NC + t];
            const float4 x0 = *(const float4*)&xs[0][k0];
            const float4 x1 = *(const float4*)&xs[1][k0];
            const float4 x2 = *(const float4*)&xs[2][k0];
            const float4 x3 = *(const float4*)&xs[3][k0];
            dd0 = fma((double)x0.x, (double)wv.x, dd0);
            dd0 = fma((double)x0.y, (double)wv.y, dd0);
            dd0 = fma((double)x0.z, (double)wv.z, dd0);
            dd0 = fma((double)x0.w, (double)wv.w, dd0);
            dd1 = fma((double)x1.x, (double)wv.x, dd1);
            dd1 = fma((double)x1.y, (double)wv.y, dd1);
            dd1 = fma((double)x1.z, (double)wv.z, dd1);
            dd1 = fma((double)x1.w, (double)wv.w, dd1);
            dd2 = fma((double)x2.x, (double)wv.x, dd2);
            dd2 = fma((double)x2.y, (double)wv.y, dd2);
            dd2 = fma((double)x2.z, (double)wv.z, dd2);
            dd2 = fma((double)x2.w, (double)wv.w, dd2);
            dd3 = fma((double)x3.x, (double)wv.x, dd3);
            dd3 = fma((double)x3.y, (double)wv.y, dd3);
            dd3 = fma((double)x3.z, (double)wv.z, dd3);
            dd3 = fma((double)x3.w, (double)wv.w, dd3);
        }

        const double csqt = (double)c_sq[t];
        const double dv[4] = {dd0, dd1, dd2, dd3};
        #pragma unroll
        for (int r = 0; r < 4; ++r) {
            double bv = csqt - 2.0 * dv[r];
            int bc = t;
            #pragma unroll
            for (int off = 1; off < 64; off <<= 1) {
                const double ov = __shfl_xor(bv, off);
                const int oc = __shfl_xor(bc, off);
                if (ov < bv || (ov == bv && oc < bc)) { bv = ov; bc = oc; }
            }
            if (lane == 0) { bvs[r * 4 + w] = bv; bcs[r * 4 + w] = bc; }
        }
        __syncthreads();
        if (t < 4) {
            double bv = bvs[t * 4];
            int bc = bcs[t * 4];
            #pragma unroll
            for (int g = 1; g < 4; ++g) {   // ascending wave = ascending codes
                const double v = bvs[t * 4 + g];
                const int c = bcs[t * 4 + g];
                if (v < bv || (v == bv && c < bc)) { bv = v; bc = c; }
            }
            bcf[t] = bc;
        }
        __syncthreads();
        // write corrected output rows directly
        #pragma unroll
        for (int r = 0; r < 4; ++r) {
            const int idx = base + r;
            if (idx < n) {
                const int bc = bcf[r];
                const int rowg = wl[idx];
                const float m = (c_sq[bc] > 0.01f) ? 1.0f : 0.0f;
                float4 v = ((const float4*)(cb + (size_t)bc * H))[t];
                v.x *= m; v.y *= m; v.z *= m; v.w *= m;
                ((float4*)(out + (size_t)rowg * H))[t] = v;
            }
        }
        __syncthreads();
    }
}

extern "C" void kernel_launch(void* const* d_in, const int* in_sizes, int n_in,
                              void* d_out, int out_size, void* d_ws, size_t ws_size,
                              hipStream_t stream) {
    const float* keys = (const float*)d_in[0];
    const float* vals = (const float*)d_in[1];
    const float* cb   = (const float*)d_in[2];
    float* out = (float*)d_out;

    // ws: c_sq[256] f32 | wt4[256K f32, packed-k float4] | wbuf[512K] u16
    //     | pbv[64K] f32 | pb2[64K] f32 | pbc[64K] i32 | wl[32K] | wl_count[1]
    float* c_sq = (float*)d_ws;
    float4* wt4 = (float4*)(c_sq + NC);
    unsigned short* wbuf = (unsigned short*)((float*)wt4 + (size_t)H * NC);
    float* pbv = (float*)(wbuf + (size_t)KSTEPS * 2048 * 8);
    float* pb2 = pbv + 65536;
    int* pbc = (int*)(pb2 + 65536);
    int* wl = pbc + 65536;
    int* wl_count = wl + WLCAP;

    const int rows = in_sizes[0] / H;  // 16384 per tensor

    prep_kernel<<<NC, 256, 0, stream>>>(cb, c_sq, wt4, wl_count);
    prep_frag_kernel<<<KSTEPS, 256, 0, stream>>>(cb, wbuf);
    dim3 g(rows / MT, 4);   // x: row tiles, y: tensor*2 + code-half
    argmin_kernel<<<g, THREADS, 0, stream>>>(keys, vals, wbuf, c_sq, pbv, pb2, pbc);
    gather_kernel<<<rows * 2 / 4, 256, 0, stream>>>(cb, c_sq, pbv, pb2, pbc, wl, wl_count, out);
    recheck_kernel<<<1024, 256, 0, stream>>>(keys, vals, wt4, c_sq, cb, wl, wl_count, out);
}

// Round 4
// 346.590 us; speedup vs baseline: 1.0282x; 1.0282x over previous
//
#include <hip/hip_runtime.h>

// FastVCompressor: VQ nearest-code + gather + sparsity mask.
//   keys [4,4096,1024] f32, values [4,4096,1024] f32, codebook [256,1024] f32
// out = concat(keys_c, values_c) f32.
//
// R9: revert R8's code-split (it halved MFMA/step but duplicated A-staging:
//     MfmaUtil 23->18, dur 88->112). Back to R7 argmin core (256 codes/block,
//     4 waves, 48 MFMA/step, 80KB LDS, 2 blocks/CU) + kernel fusion:
//   - prep_all: c_sq + wt4 (k-major float4, for recheck) + wbuf frag-pack
//     + wl_count zero, one kernel (one block per code, row staged in LDS).
//   - argmin_kernel: R7 GEMM-argmin + FUSED gather epilogue: block writes
//     masked cb[bc] rows to out directly (cb is L2-resident; HBM 90% idle).
//     Appends margin-flagged rows to worklist. No fidx/pbv round-trips.
//   - recheck: exact fp64 argmin of flagged rows, overwrites out rows.
//   5 dispatches -> 3.

#define H 1024
#define NC 256
#define MT 64
#define THREADS 256
#define BK 32
#define KSTEPS (H / BK)   // 32
#define WLCAP 32768

typedef __attribute__((ext_vector_type(8))) short bf16x8;
typedef __attribute__((ext_vector_type(4))) float f32x4;

static __device__ inline unsigned short f2bf_rne(float f) {
    unsigned u = __float_as_uint(f);
    u += 0x7FFF + ((u >> 16) & 1);
    return (unsigned short)(u >> 16);
}
static __device__ inline float bf2f(unsigned short h) {
    return __uint_as_float((unsigned)h << 16);
}
static __device__ inline void gl_lds16(const void* g, void* l) {
    __builtin_amdgcn_global_load_lds(
        (const __attribute__((address_space(1))) unsigned int*)g,
        (__attribute__((address_space(3))) unsigned int*)l, 16, 0, 0);
}

// ---------------- prep_all: c_sq + wt4 + wbuf frag-pack + count zero -------
// One block per code b. Row staged in LDS; each thread then produces one
// wbuf uint4 piece (s = t>>3, kq = (t>>1)&3, h = t&1).
// wt4 layout: float4 index (k>>2)*NC + code  holds cb[code][4k..4k+3].
// wbuf uint4 index: ((s*16 + ct)*2 + h)*64 + kq*16 + (code&15), ct = code>>4.
__global__ __launch_bounds__(256) void prep_all(const float* __restrict__ cb,
                                                float* __restrict__ c_sq,
                                                float4* __restrict__ wt4,
                                                unsigned short* __restrict__ wbuf,
                                                int* __restrict__ wl_count) {
    __shared__ float xs[H];
    __shared__ float red[4];
    const int b = blockIdx.x;
    const int t = threadIdx.x;
    if (b == 0 && t == 0) wl_count[0] = 0;
    const float4 v = *(const float4*)(cb + (size_t)b * H + 4 * t);
    *(float4*)&xs[4 * t] = v;
    wt4[(size_t)t * NC + b] = v;
    float s = v.x * v.x + v.y * v.y + v.z * v.z + v.w * v.w;
    #pragma unroll
    for (int off = 32; off > 0; off >>= 1) s += __shfl_down(s, off);
    if ((t & 63) == 0) red[t >> 6] = s;
    __syncthreads();
    if (t == 0) c_sq[b] = red[0] + red[1] + red[2] + red[3];

    const int sl = t >> 3;
    const int kq = (t >> 1) & 3;
    const int h = t & 1;
    const int k0 = sl * BK + kq * 8;
    unsigned short o[8];
    #pragma unroll
    for (int j = 0; j < 8; ++j) {
        const float x = xs[k0 + j];
        const unsigned short hi = f2bf_rne(x);
        o[j] = h ? f2bf_rne(x - bf2f(hi)) : hi;
    }
    const size_t idx = (((size_t)sl * 16 + (b >> 4)) * 2 + h) * 64 + kq * 16 + (b & 15);
    *(uint4*)(wbuf + idx * 8) = *(const uint4*)o;
}

// ---------------- main: GEMM-argmin + fused gather ----------------
__global__ __launch_bounds__(THREADS, 2) void argmin_kernel(
    const float* __restrict__ keys, const float* __restrict__ vals,
    const unsigned short* __restrict__ wbuf, const float* __restrict__ c_sq,
    const float* __restrict__ cb, int* __restrict__ wl, int* __restrict__ wl_count,
    float* __restrict__ out) {
    __shared__ uint4 b_u4[2][2048];   // 64 KB: B dbuf, frag-major
    __shared__ uint4 a_u4[2][512];    // 16 KB: A dbuf, (rt*2+h)*64 + slot

    const int t = threadIdx.x;
    const int lane = t & 63;
    const int w = t >> 6;            // wave 0..3: code-quad ct = w*4+j
    const int tensor = blockIdx.y;
    const float* __restrict__ X = tensor ? vals : keys;
    const int row0 = blockIdx.x * MT;

    // A staging slot: thread t stages (rt = t>>6, slot = lane)
    const int s_row = row0 + (t >> 6) * 16 + (lane & 15);
    const int s_kq = (lane >> 4) * 8;
    const float* __restrict__ xrow = X + (size_t)s_row * H + s_kq;

    f32x4 acc[4][4];
    #pragma unroll
    for (int i = 0; i < 4; ++i)
        #pragma unroll
        for (int j = 0; j < 4; ++j) acc[i][j] = (f32x4){0.f, 0.f, 0.f, 0.f};

    // ---- prologue: stage step 0, prefetch step 1 ----
    {
        const float4 c0 = *(const float4*)(xrow);
        const float4 c1 = *(const float4*)(xrow + 4);
        float x[8] = {c0.x, c0.y, c0.z, c0.w, c1.x, c1.y, c1.z, c1.w};
        unsigned short hi[8], lo[8];
        #pragma unroll
        for (int j = 0; j < 8; ++j) {
            hi[j] = f2bf_rne(x[j]);
            lo[j] = f2bf_rne(x[j] - bf2f(hi[j]));
        }
        a_u4[0][((t >> 6) * 2 + 0) * 64 + lane] = *(const uint4*)hi;
        a_u4[0][((t >> 6) * 2 + 1) * 64 + lane] = *(const uint4*)lo;
        const char* gsrc = (const char*)wbuf + (size_t)w * 8192 + lane * 16;
        char* ldst = (char*)&b_u4[0][0] + w * 8192;
        #pragma unroll
        for (int c = 0; c < 8; ++c) gl_lds16(gsrc + c * 1024, ldst + c * 1024);
    }
    float4 nx0 = *(const float4*)(xrow + BK);
    float4 nx1 = *(const float4*)(xrow + BK + 4);
    __syncthreads();

    for (int s = 0; s < KSTEPS; ++s) {
        const int p = s & 1;
        if (s + 1 < KSTEPS) {
            // stage step s+1 into buffer p^1 (stale since end of step s-1)
            float x[8] = {nx0.x, nx0.y, nx0.z, nx0.w, nx1.x, nx1.y, nx1.z, nx1.w};
            unsigned short hi[8], lo[8];
            #pragma unroll
            for (int j = 0; j < 8; ++j) {
                hi[j] = f2bf_rne(x[j]);
                lo[j] = f2bf_rne(x[j] - bf2f(hi[j]));
            }
            a_u4[p ^ 1][((t >> 6) * 2 + 0) * 64 + lane] = *(const uint4*)hi;
            a_u4[p ^ 1][((t >> 6) * 2 + 1) * 64 + lane] = *(const uint4*)lo;
            const char* gsrc = (const char*)wbuf + (size_t)(s + 1) * 32768 + w * 8192 + lane * 16;
            char* ldst = (char*)&b_u4[p ^ 1][0] + w * 8192;
            #pragma unroll
            for (int c = 0; c < 8; ++c) gl_lds16(gsrc + c * 1024, ldst + c * 1024);
        }
        if (s + 2 < KSTEPS) {
            nx0 = *(const float4*)(xrow + (s + 2) * BK);
            nx1 = *(const float4*)(xrow + (s + 2) * BK + 4);
        }
        // compute on buffer p
        bf16x8 ah[4], al[4], bh[4], bl[4];
        #pragma unroll
        for (int i = 0; i < 4; ++i) {
            ah[i] = ((const bf16x8*)&a_u4[p][0])[(i * 2 + 0) * 64 + lane];
            al[i] = ((const bf16x8*)&a_u4[p][0])[(i * 2 + 1) * 64 + lane];
        }
        #pragma unroll
        for (int j = 0; j < 4; ++j) {
            const int ct = w * 4 + j;
            bh[j] = ((const bf16x8*)&b_u4[p][0])[(ct * 2 + 0) * 64 + lane];
            bl[j] = ((const bf16x8*)&b_u4[p][0])[(ct * 2 + 1) * 64 + lane];
        }
        #pragma unroll
        for (int i = 0; i < 4; ++i)
            #pragma unroll
            for (int j = 0; j < 4; ++j) {
                acc[i][j] = __builtin_amdgcn_mfma_f32_16x16x32_bf16(ah[i], bl[j], acc[i][j], 0, 0, 0);
                acc[i][j] = __builtin_amdgcn_mfma_f32_16x16x32_bf16(al[i], bh[j], acc[i][j], 0, 0, 0);
                acc[i][j] = __builtin_amdgcn_mfma_f32_16x16x32_bf16(ah[i], bh[j], acc[i][j], 0, 0, 0);
            }
        __syncthreads();
    }

    // ---- per-row argmin with best-2 tracking ----
    float csq[4];
    #pragma unroll
    for (int j = 0; j < 4; ++j) csq[j] = c_sq[w * 64 + j * 16 + (lane & 15)];

    float* rv = (float*)&a_u4[0][0];        // [64][4]
    int* ri = (int*)&a_u4[0][0] + 256;      // [64][4]
    float* r2 = (float*)&a_u4[0][0] + 512;  // [64][4]
    int* fbc = (int*)&a_u4[0][0] + 768;     // [64] final code per row

    #pragma unroll
    for (int i = 0; i < 4; ++i) {
        #pragma unroll
        for (int r = 0; r < 4; ++r) {
            const int row = i * 16 + (lane >> 4) * 4 + r;
            float bv = csq[0] - 2.0f * acc[i][0][r];
            int bc = w * 64 + (lane & 15);
            float b2 = 3.4e38f;
            #pragma unroll
            for (int j = 1; j < 4; ++j) {
                const float v = csq[j] - 2.0f * acc[i][j][r];
                if (v < bv) { b2 = bv; bv = v; bc = w * 64 + j * 16 + (lane & 15); }
                else b2 = fminf(b2, v);
            }
            #pragma unroll
            for (int off = 1; off < 16; off <<= 1) {
                const float ov = __shfl_xor(bv, off);
                const int oc = __shfl_xor(bc, off);
                const float ov2 = __shfl_xor(b2, off);
                const float nb2 = fminf(fmaxf(bv, ov), fminf(b2, ov2));
                if (ov < bv || (ov == bv && oc < bc)) { bv = ov; bc = oc; }
                b2 = nb2;
            }
            if ((lane & 15) == 0) {
                rv[row * 4 + w] = bv;
                ri[row * 4 + w] = bc;
                r2[row * 4 + w] = b2;
            }
        }
    }
    __syncthreads();
    if (t < MT) {
        float bv = rv[t * 4];
        int bc = ri[t * 4];
        float b2 = r2[t * 4];
        #pragma unroll
        for (int g = 1; g < 4; ++g) {        // ascending wave = ascending codes
            const float v = rv[t * 4 + g];
            const int c = ri[t * 4 + g];
            const float v2 = r2[t * 4 + g];
            const float nb2 = fminf(fmaxf(bv, v), fminf(b2, v2));
            if (v < bv || (v == bv && c < bc)) { bv = v; bc = c; }
            b2 = nb2;
        }
        fbc[t] = bc;
        if (b2 - bv < 0.15f) {
            const size_t rowg = (size_t)tensor * (gridDim.x * MT) + row0 + t;
            const int pos = atomicAdd(wl_count, 1);
            if (pos < WLCAP) wl[pos] = (int)rowg;
        }
    }
    __syncthreads();

    // ---- fused gather: each wave writes 16 rows of masked cb[bc] ----
    for (int r = w; r < MT; r += 4) {
        const int bc = fbc[r];
        const float m = (c_sq[bc] > 0.01f) ? 1.0f : 0.0f;
        const size_t rowg = (size_t)tensor * (gridDim.x * MT) + row0 + r;
        const float4* __restrict__ src = (const float4*)(cb + (size_t)bc * H);
        float4* __restrict__ dst = (float4*)(out + rowg * H);
        #pragma unroll
        for (int j = 0; j < 4; ++j) {
            float4 v = src[lane + 64 * j];
            v.x *= m; v.y *= m; v.z *= m; v.w *= m;
            dst[lane + 64 * j] = v;
        }
    }
}

// ---------------- exact fp64 recheck of worklist rows, writes out directly ---
__global__ __launch_bounds__(256) void recheck_kernel(
    const float* __restrict__ keys, const float* __restrict__ vals,
    const float4* __restrict__ wt4, const float* __restrict__ c_sq,
    const float* __restrict__ cb, const int* __restrict__ wl,
    const int* __restrict__ wl_count, float* __restrict__ out) {
    __shared__ float xs[4][H];       // 16 KB
    __shared__ double bvs[16];
    __shared__ int bcs[16];
    __shared__ int bcf[4];

    const int t = threadIdx.x;
    const int w = t >> 6;
    const int lane = t & 63;
    int n = wl_count[0];
    if (n > WLCAP) n = WLCAP;
    if (n == 0) return;

    for (int base = blockIdx.x * 4; base < n; base += gridDim.x * 4) {
        // wave w loads row (base + w); clamp duplicates are computed but not written
        {
            const int idx = base + w;
            const int rowg = wl[idx < n ? idx : n - 1];
            const float* __restrict__ X =
                ((rowg >> 14) ? vals : keys) + (size_t)(rowg & 16383) * H;
            #pragma unroll
            for (int j = 0; j < 4; ++j)
                ((float4*)&xs[w][0])[lane + 64 * j] = ((const float4*)X)[lane + 64 * j];
        }
        __syncthreads();

        double dd0 = 0.0, dd1 = 0.0, dd2 = 0.0, dd3 = 0.0;
        for (int k0 = 0; k0 < H; k0 += 4) {
            const float4 wv = wt4[(size_t)(k0 >> 2) * NC + t];
            const float4 x0 = *(const float4*)&xs[0][k0];
            const float4 x1 = *(const float4*)&xs[1][k0];
            const float4 x2 = *(const float4*)&xs[2][k0];
            const float4 x3 = *(const float4*)&xs[3][k0];
            dd0 = fma((double)x0.x, (double)wv.x, dd0);
            dd0 = fma((double)x0.y, (double)wv.y, dd0);
            dd0 = fma((double)x0.z, (double)wv.z, dd0);
            dd0 = fma((double)x0.w, (double)wv.w, dd0);
            dd1 = fma((double)x1.x, (double)wv.x, dd1);
            dd1 = fma((double)x1.y, (double)wv.y, dd1);
            dd1 = fma((double)x1.z, (double)wv.z, dd1);
            dd1 = fma((double)x1.w, (double)wv.w, dd1);
            dd2 = fma((double)x2.x, (double)wv.x, dd2);
            dd2 = fma((double)x2.y, (double)wv.y, dd2);
            dd2 = fma((double)x2.z, (double)wv.z, dd2);
            dd2 = fma((double)x2.w, (double)wv.w, dd2);
            dd3 = fma((double)x3.x, (double)wv.x, dd3);
            dd3 = fma((double)x3.y, (double)wv.y, dd3);
            dd3 = fma((double)x3.z, (double)wv.z, dd3);
            dd3 = fma((double)x3.w, (double)wv.w, dd3);
        }

        const double csqt = (double)c_sq[t];
        const double dv[4] = {dd0, dd1, dd2, dd3};
        #pragma unroll
        for (int r = 0; r < 4; ++r) {
            double bv = csqt - 2.0 * dv[r];
            int bc = t;
            #pragma unroll
            for (int off = 1; off < 64; off <<= 1) {
                const double ov = __shfl_xor(bv, off);
                const int oc = __shfl_xor(bc, off);
                if (ov < bv || (ov == bv && oc < bc)) { bv = ov; bc = oc; }
            }
            if (lane == 0) { bvs[r * 4 + w] = bv; bcs[r * 4 + w] = bc; }
        }
        __syncthreads();
        if (t < 4) {
            double bv = bvs[t * 4];
            int bc = bcs[t * 4];
            #pragma unroll
            for (int g = 1; g < 4; ++g) {   // ascending wave = ascending codes
                const double v = bvs[t * 4 + g];
                const int c = bcs[t * 4 + g];
                if (v < bv || (v == bv && c < bc)) { bv = v; bc = c; }
            }
            bcf[t] = bc;
        }
        __syncthreads();
        // write corrected output rows directly
        #pragma unroll
        for (int r = 0; r < 4; ++r) {
            const int idx = base + r;
            if (idx < n) {
                const int bc = bcf[r];
                const int rowg = wl[idx];
                const float m = (c_sq[bc] > 0.01f) ? 1.0f : 0.0f;
                float4 v = ((const float4*)(cb + (size_t)bc * H))[t];
                v.x *= m; v.y *= m; v.z *= m; v.w *= m;
                ((float4*)(out + (size_t)rowg * H))[t] = v;
            }
        }
        __syncthreads();
    }
}

extern "C" void kernel_launch(void* const* d_in, const int* in_sizes, int n_in,
                              void* d_out, int out_size, void* d_ws, size_t ws_size,
                              hipStream_t stream) {
    const float* keys = (const float*)d_in[0];
    const float* vals = (const float*)d_in[1];
    const float* cb   = (const float*)d_in[2];
    float* out = (float*)d_out;

    // ws: c_sq[256] f32 | wt4[256K f32, packed-k float4] | wbuf[512K] u16
    //     | wl[32K] i32 | wl_count[1]
    float* c_sq = (float*)d_ws;
    float4* wt4 = (float4*)(c_sq + NC);
    unsigned short* wbuf = (unsigned short*)((float*)wt4 + (size_t)H * NC);
    int* wl = (int*)(wbuf + (size_t)KSTEPS * 2048 * 8);
    int* wl_count = wl + WLCAP;

    const int rows = in_sizes[0] / H;  // 16384 per tensor

    prep_all<<<NC, 256, 0, stream>>>(cb, c_sq, wt4, wbuf, wl_count);
    dim3 g(rows / MT, 2);
    argmin_kernel<<<g, THREADS, 0, stream>>>(keys, vals, wbuf, c_sq, cb, wl, wl_count, out);
    recheck_kernel<<<1024, 256, 0, stream>>>(keys, vals, wt4, c_sq, cb, wl, wl_count, out);
}

// Round 5
// 335.128 us; speedup vs baseline: 1.0634x; 1.0342x over previous
//
#include <hip/hip_runtime.h>

// FastVCompressor: VQ nearest-code + gather + sparsity mask.
//   keys [4,4096,1024] f32, values [4,4096,1024] f32, codebook [256,1024] f32
// out = concat(keys_c, values_c) f32.
//
// R10: revert R9's gather fusion (epilogue write burst cost +46us > standalone
//      gather's ~31us). Keep prep_all fusion + direct-write recheck.
//   Core change: argmin 256 -> 512 threads (8 waves/block), same 80KB LDS ->
//   2 blocks/CU = 16 waves/CU = 4 waves/SIMD (was 2). Same math/tile:
//   each wave owns 2 code-tiles (acc[4][2], 24 MFMA/step); A-staging split
//   1 float4 -> hi/lo uint2 per thread (halves per-thread convert VALU);
//   B-staging 4 gl_lds/wave. Latency-bound structure -> 2x TLP.
//   Pipeline: prep_all -> argmin -> gather -> recheck (direct out overwrite).

#define H 1024
#define NC 256
#define MT 64
#define THREADS 512
#define BK 32
#define KSTEPS (H / BK)   // 32
#define WLCAP 32768

typedef __attribute__((ext_vector_type(8))) short bf16x8;
typedef __attribute__((ext_vector_type(4))) float f32x4;

static __device__ inline unsigned short f2bf_rne(float f) {
    unsigned u = __float_as_uint(f);
    u += 0x7FFF + ((u >> 16) & 1);
    return (unsigned short)(u >> 16);
}
static __device__ inline float bf2f(unsigned short h) {
    return __uint_as_float((unsigned)h << 16);
}
static __device__ inline void gl_lds16(const void* g, void* l) {
    __builtin_amdgcn_global_load_lds(
        (const __attribute__((address_space(1))) unsigned int*)g,
        (__attribute__((address_space(3))) unsigned int*)l, 16, 0, 0);
}
static __device__ inline void cvt4(const float4 c, uint2& hi, uint2& lo) {
    unsigned short h[4], l[4];
    const float x[4] = {c.x, c.y, c.z, c.w};
    #pragma unroll
    for (int j = 0; j < 4; ++j) {
        h[j] = f2bf_rne(x[j]);
        l[j] = f2bf_rne(x[j] - bf2f(h[j]));
    }
    hi = *(const uint2*)h;
    lo = *(const uint2*)l;
}

// ---------------- prep_all: c_sq + wt4 + wbuf frag-pack + count zero -------
// One block per code b. Row staged in LDS; each thread then produces one
// wbuf uint4 piece (s = t>>3, kq = (t>>1)&3, h = t&1).
// wt4 layout: float4 index (k>>2)*NC + code  holds cb[code][4k..4k+3].
// wbuf uint4 index: ((s*16 + ct)*2 + h)*64 + kq*16 + (code&15), ct = code>>4.
__global__ __launch_bounds__(256) void prep_all(const float* __restrict__ cb,
                                                float* __restrict__ c_sq,
                                                float4* __restrict__ wt4,
                                                unsigned short* __restrict__ wbuf,
                                                int* __restrict__ wl_count) {
    __shared__ float xs[H];
    __shared__ float red[4];
    const int b = blockIdx.x;
    const int t = threadIdx.x;
    if (b == 0 && t == 0) wl_count[0] = 0;
    const float4 v = *(const float4*)(cb + (size_t)b * H + 4 * t);
    *(float4*)&xs[4 * t] = v;
    wt4[(size_t)t * NC + b] = v;
    float s = v.x * v.x + v.y * v.y + v.z * v.z + v.w * v.w;
    #pragma unroll
    for (int off = 32; off > 0; off >>= 1) s += __shfl_down(s, off);
    if ((t & 63) == 0) red[t >> 6] = s;
    __syncthreads();
    if (t == 0) c_sq[b] = red[0] + red[1] + red[2] + red[3];

    const int sl = t >> 3;
    const int kq = (t >> 1) & 3;
    const int h = t & 1;
    const int k0 = sl * BK + kq * 8;
    unsigned short o[8];
    #pragma unroll
    for (int j = 0; j < 8; ++j) {
        const float x = xs[k0 + j];
        const unsigned short hi = f2bf_rne(x);
        o[j] = h ? f2bf_rne(x - bf2f(hi)) : hi;
    }
    const size_t idx = (((size_t)sl * 16 + (b >> 4)) * 2 + h) * 64 + kq * 16 + (b & 15);
    *(uint4*)(wbuf + idx * 8) = *(const uint4*)o;
}

// ---------------- main: GEMM-argmin, 8 waves, writes fidx + worklist -------
__global__ __launch_bounds__(THREADS, 4) void argmin_kernel(
    const float* __restrict__ keys, const float* __restrict__ vals,
    const unsigned short* __restrict__ wbuf, const float* __restrict__ c_sq,
    int* __restrict__ fidx_g, int* __restrict__ wl, int* __restrict__ wl_count) {
    __shared__ uint4 b_u4[2][2048];   // 64 KB: B dbuf, frag-major (16 cts)
    __shared__ uint4 a_u4[2][512];    // 16 KB: A dbuf, (rt*2+h)*64 + kq4*16 + r15

    const int t = threadIdx.x;
    const int lane = t & 63;
    const int w = t >> 6;            // wave 0..7: code pair ct = {2w, 2w+1}
    const int tensor = blockIdx.y;
    const float* __restrict__ X = tensor ? vals : keys;
    const int row0 = blockIdx.x * MT;

    // A staging: thread t handles one float4: row = rt*16 + (tt&15), k-quad kq8
    const int rt = t >> 7;           // 0..3
    const int tt = t & 127;
    const int r15 = tt & 15;
    const int kq8 = tt >> 4;         // 0..7 (float4 within the 32-k step)
    const float* __restrict__ xrow = X + (size_t)(row0 + rt * 16 + r15) * H + kq8 * 4;
    const int a_hi = ((rt * 2) * 64 + (kq8 >> 1) * 16 + r15) * 2 + (kq8 & 1);
    const int a_lo = a_hi + 128;

    f32x4 acc[4][2];
    #pragma unroll
    for (int i = 0; i < 4; ++i)
        #pragma unroll
        for (int j = 0; j < 2; ++j) acc[i][j] = (f32x4){0.f, 0.f, 0.f, 0.f};

    // ---- prologue: stage step 0, prefetch step 1 ----
    {
        uint2 hi, lo;
        cvt4(*(const float4*)(xrow), hi, lo);
        uint2* a2 = (uint2*)&a_u4[0][0];
        a2[a_hi] = hi;
        a2[a_lo] = lo;
        const char* gsrc = (const char*)wbuf + (size_t)w * 4096 + lane * 16;
        char* ldst = (char*)&b_u4[0][0] + w * 4096;
        #pragma unroll
        for (int c = 0; c < 4; ++c) gl_lds16(gsrc + c * 1024, ldst + c * 1024);
    }
    float4 nx = *(const float4*)(xrow + BK);
    __syncthreads();

    for (int s = 0; s < KSTEPS; ++s) {
        const int p = s & 1;
        if (s + 1 < KSTEPS) {
            // stage step s+1 into buffer p^1 (stale since end of step s-1)
            uint2 hi, lo;
            cvt4(nx, hi, lo);
            uint2* a2 = (uint2*)&a_u4[p ^ 1][0];
            a2[a_hi] = hi;
            a2[a_lo] = lo;
            const char* gsrc = (const char*)wbuf + (size_t)(s + 1) * 32768 +
                               (size_t)w * 4096 + lane * 16;
            char* ldst = (char*)&b_u4[p ^ 1][0] + w * 4096;
            #pragma unroll
            for (int c = 0; c < 4; ++c) gl_lds16(gsrc + c * 1024, ldst + c * 1024);
        }
        if (s + 2 < KSTEPS) nx = *(const float4*)(xrow + (s + 2) * BK);

        // compute on buffer p
        bf16x8 ah[4], al[4], bh[2], bl[2];
        #pragma unroll
        for (int i = 0; i < 4; ++i) {
            ah[i] = ((const bf16x8*)&a_u4[p][0])[(i * 2 + 0) * 64 + lane];
            al[i] = ((const bf16x8*)&a_u4[p][0])[(i * 2 + 1) * 64 + lane];
        }
        #pragma unroll
        for (int j = 0; j < 2; ++j) {
            const int ct = w * 2 + j;
            bh[j] = ((const bf16x8*)&b_u4[p][0])[(ct * 2 + 0) * 64 + lane];
            bl[j] = ((const bf16x8*)&b_u4[p][0])[(ct * 2 + 1) * 64 + lane];
        }
        #pragma unroll
        for (int i = 0; i < 4; ++i)
            #pragma unroll
            for (int j = 0; j < 2; ++j) {
                acc[i][j] = __builtin_amdgcn_mfma_f32_16x16x32_bf16(ah[i], bl[j], acc[i][j], 0, 0, 0);
                acc[i][j] = __builtin_amdgcn_mfma_f32_16x16x32_bf16(al[i], bh[j], acc[i][j], 0, 0, 0);
                acc[i][j] = __builtin_amdgcn_mfma_f32_16x16x32_bf16(ah[i], bh[j], acc[i][j], 0, 0, 0);
            }
        __syncthreads();
    }

    // ---- per-row argmin with best-2 tracking (wave w covers codes [32w,32w+32)) --
    float csq[2];
    #pragma unroll
    for (int j = 0; j < 2; ++j) csq[j] = c_sq[w * 32 + j * 16 + (lane & 15)];

    float* rv = (float*)&a_u4[0][0];        // [64][8]
    int* ri = (int*)&a_u4[0][0] + 512;      // [64][8]
    float* r2 = (float*)&a_u4[0][0] + 1024; // [64][8]

    #pragma unroll
    for (int i = 0; i < 4; ++i) {
        #pragma unroll
        for (int r = 0; r < 4; ++r) {
            const int row = i * 16 + (lane >> 4) * 4 + r;
            float bv = csq[0] - 2.0f * acc[i][0][r];
            int bc = w * 32 + (lane & 15);
            float b2;
            {
                const float v = csq[1] - 2.0f * acc[i][1][r];
                if (v < bv) { b2 = bv; bv = v; bc += 16; }
                else b2 = v;
            }
            #pragma unroll
            for (int off = 1; off < 16; off <<= 1) {
                const float ov = __shfl_xor(bv, off);
                const int oc = __shfl_xor(bc, off);
                const float ov2 = __shfl_xor(b2, off);
                const float nb2 = fminf(fmaxf(bv, ov), fminf(b2, ov2));
                if (ov < bv || (ov == bv && oc < bc)) { bv = ov; bc = oc; }
                b2 = nb2;
            }
            if ((lane & 15) == 0) {
                rv[row * 8 + w] = bv;
                ri[row * 8 + w] = bc;
                r2[row * 8 + w] = b2;
            }
        }
    }
    __syncthreads();
    if (t < MT) {
        float bv = rv[t * 8];
        int bc = ri[t * 8];
        float b2 = r2[t * 8];
        #pragma unroll
        for (int g = 1; g < 8; ++g) {        // ascending wave = ascending codes
            const float v = rv[t * 8 + g];
            const int c = ri[t * 8 + g];
            const float v2 = r2[t * 8 + g];
            const float nb2 = fminf(fmaxf(bv, v), fminf(b2, v2));
            if (v < bv || (v == bv && c < bc)) { bv = v; bc = c; }
            b2 = nb2;
        }
        const size_t rowg = (size_t)tensor * (gridDim.x * MT) + row0 + t;
        fidx_g[rowg] = bc;
        if (b2 - bv < 0.15f) {
            const int pos = atomicAdd(wl_count, 1);
            if (pos < WLCAP) wl[pos] = (int)rowg;
        }
    }
}

// ---------------- gather ----------------
__global__ __launch_bounds__(256) void gather_kernel(
    const float* __restrict__ cb, const float* __restrict__ c_sq,
    const int* __restrict__ fidx_g, float* __restrict__ out) {
    const int t = threadIdx.x;
    const int row = blockIdx.x * 4 + (t >> 6);
    const int lane = t & 63;
    const int ci = fidx_g[row];
    const float m = (c_sq[ci] > 0.01f) ? 1.0f : 0.0f;
    const float4* __restrict__ src = (const float4*)(cb + (size_t)ci * H);
    float4* __restrict__ dst = (float4*)(out + (size_t)row * H);
    #pragma unroll
    for (int j = 0; j < 4; ++j) {
        float4 v = src[lane + 64 * j];
        v.x *= m; v.y *= m; v.z *= m; v.w *= m;
        dst[lane + 64 * j] = v;
    }
}

// ---------------- exact fp64 recheck of worklist rows, writes out directly ---
__global__ __launch_bounds__(256) void recheck_kernel(
    const float* __restrict__ keys, const float* __restrict__ vals,
    const float4* __restrict__ wt4, const float* __restrict__ c_sq,
    const float* __restrict__ cb, const int* __restrict__ wl,
    const int* __restrict__ wl_count, float* __restrict__ out) {
    __shared__ float xs[4][H];       // 16 KB
    __shared__ double bvs[16];
    __shared__ int bcs[16];
    __shared__ int bcf[4];

    const int t = threadIdx.x;
    const int w = t >> 6;
    const int lane = t & 63;
    int n = wl_count[0];
    if (n > WLCAP) n = WLCAP;
    if (n == 0) return;

    for (int base = blockIdx.x * 4; base < n; base += gridDim.x * 4) {
        // wave w loads row (base + w); clamp duplicates are computed but not written
        {
            const int idx = base + w;
            const int rowg = wl[idx < n ? idx : n - 1];
            const float* __restrict__ X =
                ((rowg >> 14) ? vals : keys) + (size_t)(rowg & 16383) * H;
            #pragma unroll
            for (int j = 0; j < 4; ++j)
                ((float4*)&xs[w][0])[lane + 64 * j] = ((const float4*)X)[lane + 64 * j];
        }
        __syncthreads();

        double dd0 = 0.0, dd1 = 0.0, dd2 = 0.0, dd3 = 0.0;
        for (int k0 = 0; k0 < H; k0 += 4) {
            const float4 wv = wt4[(size_t)(k0 >> 2) * NC + t];
            const float4 x0 = *(const float4*)&xs[0][k0];
            const float4 x1 = *(const float4*)&xs[1][k0];
            const float4 x2 = *(const float4*)&xs[2][k0];
            const float4 x3 = *(const float4*)&xs[3][k0];
            dd0 = fma((double)x0.x, (double)wv.x, dd0);
            dd0 = fma((double)x0.y, (double)wv.y, dd0);
            dd0 = fma((double)x0.z, (double)wv.z, dd0);
            dd0 = fma((double)x0.w, (double)wv.w, dd0);
            dd1 = fma((double)x1.x, (double)wv.x, dd1);
            dd1 = fma((double)x1.y, (double)wv.y, dd1);
            dd1 = fma((double)x1.z, (double)wv.z, dd1);
            dd1 = fma((double)x1.w, (double)wv.w, dd1);
            dd2 = fma((double)x2.x, (double)wv.x, dd2);
            dd2 = fma((double)x2.y, (double)wv.y, dd2);
            dd2 = fma((double)x2.z, (double)wv.z, dd2);
            dd2 = fma((double)x2.w, (double)wv.w, dd2);
            dd3 = fma((double)x3.x, (double)wv.x, dd3);
            dd3 = fma((double)x3.y, (double)wv.y, dd3);
            dd3 = fma((double)x3.z, (double)wv.z, dd3);
            dd3 = fma((double)x3.w, (double)wv.w, dd3);
        }

        const double csqt = (double)c_sq[t];
        const double dv[4] = {dd0, dd1, dd2, dd3};
        #pragma unroll
        for (int r = 0; r < 4; ++r) {
            double bv = csqt - 2.0 * dv[r];
            int bc = t;
            #pragma unroll
            for (int off = 1; off < 64; off <<= 1) {
                const double ov = __shfl_xor(bv, off);
                const int oc = __shfl_xor(bc, off);
                if (ov < bv || (ov == bv && oc < bc)) { bv = ov; bc = oc; }
            }
            if (lane == 0) { bvs[r * 4 + w] = bv; bcs[r * 4 + w] = bc; }
        }
        __syncthreads();
        if (t < 4) {
            double bv = bvs[t * 4];
            int bc = bcs[t * 4];
            #pragma unroll
            for (int g = 1; g < 4; ++g) {   // ascending wave = ascending codes
                const double v = bvs[t * 4 + g];
                const int c = bcs[t * 4 + g];
                if (v < bv || (v == bv && c < bc)) { bv = v; bc = c; }
            }
            bcf[t] = bc;
        }
        __syncthreads();
        // write corrected output rows directly
        #pragma unroll
        for (int r = 0; r < 4; ++r) {
            const int idx = base + r;
            if (idx < n) {
                const int bc = bcf[r];
                const int rowg = wl[idx];
                const float m = (c_sq[bc] > 0.01f) ? 1.0f : 0.0f;
                float4 v = ((const float4*)(cb + (size_t)bc * H))[t];
                v.x *= m; v.y *= m; v.z *= m; v.w *= m;
                ((float4*)(out + (size_t)rowg * H))[t] = v;
            }
        }
        __syncthreads();
    }
}

extern "C" void kernel_launch(void* const* d_in, const int* in_sizes, int n_in,
                              void* d_out, int out_size, void* d_ws, size_t ws_size,
                              hipStream_t stream) {
    const float* keys = (const float*)d_in[0];
    const float* vals = (const float*)d_in[1];
    const float* cb   = (const float*)d_in[2];
    float* out = (float*)d_out;

    // ws: c_sq[256] f32 | wt4[256K f32, packed-k float4] | wbuf[512K] u16
    //     | fidx[32K] i32 | wl[32K] i32 | wl_count[1]
    float* c_sq = (float*)d_ws;
    float4* wt4 = (float4*)(c_sq + NC);
    unsigned short* wbuf = (unsigned short*)((float*)wt4 + (size_t)H * NC);
    int* fidx_g = (int*)(wbuf + (size_t)KSTEPS * 2048 * 8);
    int* wl = fidx_g + 32768;
    int* wl_count = wl + WLCAP;

    const int rows = in_sizes[0] / H;  // 16384 per tensor

    prep_all<<<NC, 256, 0, stream>>>(cb, c_sq, wt4, wbuf, wl_count);
    dim3 g(rows / MT, 2);
    argmin_kernel<<<g, THREADS, 0, stream>>>(keys, vals, wbuf, c_sq, fidx_g, wl, wl_count);
    gather_kernel<<<rows * 2 / 4, 256, 0, stream>>>(cb, c_sq, fidx_g, out);
    recheck_kernel<<<1024, 256, 0, stream>>>(keys, vals, wt4, c_sq, cb, wl, wl_count, out);
}